// Round 14
// baseline (432.123 us; speedup 1.0000x reference)
//
#include <hip/hip_runtime.h>
#include <math.h>

#define NN 4096
#define DD 512
#define ELL 128

typedef unsigned long long u64;
typedef __attribute__((ext_vector_type(8))) short short8;
typedef __attribute__((ext_vector_type(8))) unsigned short ushort8;
typedef __attribute__((ext_vector_type(4))) float f32x4;

static __device__ __forceinline__ unsigned short f2bf(float f) {
  unsigned u = __float_as_uint(f);
  unsigned r = (u + 0x7fffu + ((u >> 16) & 1u)) >> 16;
  return (unsigned short)r;
}
static __device__ __forceinline__ float bf2f(unsigned short h) {
  return __uint_as_float(((unsigned)h) << 16);
}

// ---- build ELL: wave/row, 16-deep load preload + independent chunk ballots --
struct Build3 {
  const float *adj0, *adj1, *adj2;
  int *c0, *c1, *c2;
  int *n0, *n1, *n2;
};

__global__ __launch_bounds__(256) void k_build3(Build3 p) {
  const int s = blockIdx.y;
  const float* adj = s == 0 ? p.adj0 : (s == 1 ? p.adj1 : p.adj2);
  int* cols = s == 0 ? p.c0 : (s == 1 ? p.c1 : p.c2);
  int* cnt  = s == 0 ? p.n0 : (s == 1 ? p.n1 : p.n2);
  const int wv = threadIdx.x >> 6;
  const int lane = threadIdx.x & 63;
  const int r = blockIdx.x * 4 + wv;
  const float* row = adj + (size_t)r * NN;
  int* rc = cols + (size_t)r * ELL;
  const u64 below = (1ull << lane) - 1ull;

  // all 16 loads issued up-front (256B/lane in flight)
  float4 v[16];
#pragma unroll
  for (int c = 0; c < 16; c++)
    v[c] = *(const float4*)(row + c * 256 + lane * 4);

  // per-chunk ballots: no cross-chunk dependency
  int pre[16], tot[16];
#pragma unroll
  for (int c = 0; c < 16; c++) {
    u64 m0 = __ballot(v[c].x > 0.f);
    u64 m1 = __ballot(v[c].y > 0.f);
    u64 m2 = __ballot(v[c].z > 0.f);
    u64 m3 = __ballot(v[c].w > 0.f);
    pre[c] = __popcll(m0 & below) + __popcll(m1 & below) +
             __popcll(m2 & below) + __popcll(m3 & below);
    tot[c] = __popcll(m0) + __popcll(m1) + __popcll(m2) + __popcll(m3);
  }

  // serial part is just 16 adds
  int base = 0;
#pragma unroll
  for (int c = 0; c < 16; c++) {
    int off = base + pre[c];
    const int cb = c * 256 + lane * 4;
    if (v[c].x > 0.f) { if (off < ELL) rc[off] = cb + 0; off++; }
    if (v[c].y > 0.f) { if (off < ELL) rc[off] = cb + 1; off++; }
    if (v[c].z > 0.f) { if (off < ELL) rc[off] = cb + 2; off++; }
    if (v[c].w > 0.f) { if (off < ELL) rc[off] = cb + 3; off++; }
    base += tot[c];
  }
  if (lane == 0) cnt[r] = base < ELL ? base : ELL;
}

// ---- split f32 matrix into 3 bf16 matrices in MFMA-fragment tile order ------
struct SplitE { const float* src; unsigned short* dst; int rows; int bstyle; };
struct Split4 { SplitE e[4]; };

__global__ __launch_bounds__(256) void k_split(Split4 p) {
  SplitE e = p.e[blockIdx.y];
  if (!e.src) return;
  const int oct = blockIdx.x * 256 + threadIdx.x;
  if (oct >= e.rows * 64) return;
  float v[8];
  size_t toff;
  if (!e.bstyle) {
    const int m = oct >> 6, kg = oct & 63;
    const float* sp = e.src + (size_t)m * 512 + kg * 8;
    float4 u0 = *(const float4*)sp;
    float4 u1 = *(const float4*)(sp + 4);
    v[0] = u0.x; v[1] = u0.y; v[2] = u0.z; v[3] = u0.w;
    v[4] = u1.x; v[5] = u1.y; v[6] = u1.z; v[7] = u1.w;
    toff = ((size_t)(m >> 7) * 16 + (kg >> 2)) * 4096 +
           (size_t)((m & 127) >> 4) * 512 + (size_t)(kg & 3) * 128 +
           (size_t)(m & 15) * 8;
  } else {
    const int n = oct & 511, kog = oct >> 9;
    const int k0 = kog * 8;
#pragma unroll
    for (int i = 0; i < 8; i++) v[i] = e.src[(size_t)(k0 + i) * 512 + n];
    toff = ((size_t)(n >> 7) * 16 + (kog >> 2)) * 4096 +
           (size_t)((n & 127) >> 4) * 512 + (size_t)(kog & 3) * 128 +
           (size_t)(n & 15) * 8;
  }
  ushort8 h0, h1, h2;
#pragma unroll
  for (int i = 0; i < 8; i++) {
    float f = v[i];
    unsigned short a0 = f2bf(f);
    float r1 = f - bf2f(a0);
    unsigned short a1 = f2bf(r1);
    float r2 = r1 - bf2f(a1);
    unsigned short a2 = f2bf(r2);
    h0[i] = a0; h1[i] = a1; h2[i] = a2;
  }
  const size_t stride = (size_t)e.rows * 512;
  *(ushort8*)(e.dst + toff) = h0;
  *(ushort8*)(e.dst + stride + toff) = h1;
  *(ushort8*)(e.dst + 2 * stride + toff) = h2;
}

// ---- plain f32 -> bf16 row-major copy (for PV gather) -----------------------
struct ToBf {
  const float *s0, *s1;
  unsigned short *d0, *d1;
};

__global__ __launch_bounds__(256) void k_tobf16(ToBf p) {
  const float* s = blockIdx.y ? p.s1 : p.s0;
  unsigned short* d = blockIdx.y ? p.d1 : p.d0;
  const size_t i = ((size_t)blockIdx.x * 256 + threadIdx.x) * 8;
  float4 a = *(const float4*)(s + i);
  float4 b = *(const float4*)(s + i + 4);
  ushort8 h;
  h[0] = f2bf(a.x); h[1] = f2bf(a.y); h[2] = f2bf(a.z); h[3] = f2bf(a.w);
  h[4] = f2bf(b.x); h[5] = f2bf(b.y); h[6] = f2bf(b.z); h[7] = f2bf(b.w);
  *(ushort8*)(d + i) = h;
}

// ---- MFMA GEMM: C[rows x 512] = A @ B (+bias), exact via 3-way bf16 split ---
struct GmP {
  const unsigned short *A0, *A1, *A2;
  const unsigned short *B0, *B1, *B2;
  const float *b0, *b1, *b2;
  float *C0, *C1, *C2;
  size_t sA, sB;
};

#define MMTERM(sa)                                                          \
  _Pragma("unroll")                                                         \
  for (int mi = 0; mi < 4; mi++) {                                          \
    _Pragma("unroll")                                                       \
    for (int ni = 0; ni < 4; ni++)                                          \
      acc[mi][ni] = __builtin_amdgcn_mfma_f32_16x16x32_bf16(                \
          af[sa][mi], bf[ni], acc[mi][ni], 0, 0, 0);                        \
  }

__global__ __launch_bounds__(256) void k_gemm_mfma(GmP p) {
  __shared__ __align__(16) unsigned short Al[3][4096];
  __shared__ __align__(16) unsigned short Bl[3][4096];
  const int tid = threadIdx.x;
  const int mat = blockIdx.y >> 2;
  const int nb = blockIdx.y & 3;
  const int mb = blockIdx.x;
  const unsigned short* A = mat == 0 ? p.A0 : (mat == 1 ? p.A1 : p.A2);
  const unsigned short* B = mat == 0 ? p.B0 : (mat == 1 ? p.B1 : p.B2);
  const float* bias = mat == 0 ? p.b0 : (mat == 1 ? p.b1 : p.b2);
  float* C = mat == 0 ? p.C0 : (mat == 1 ? p.C1 : p.C2);
  const int lane = tid & 63, w = tid >> 6, wr = w >> 1, wc = w & 1;
  const size_t s8A = p.sA >> 3, s8B = p.sB >> 3;

  f32x4 acc[4][4];
#pragma unroll
  for (int mi = 0; mi < 4; mi++)
#pragma unroll
    for (int ni = 0; ni < 4; ni++) acc[mi][ni] = (f32x4){0.f, 0.f, 0.f, 0.f};

  for (int kb = 0; kb < 16; kb++) {
    const short8* ga = (const short8*)(A + ((size_t)mb * 16 + kb) * 4096);
    const short8* gb = (const short8*)(B + ((size_t)nb * 16 + kb) * 4096);
    __syncthreads();
#pragma unroll
    for (int s = 0; s < 3; s++) {
#pragma unroll
      for (int c = 0; c < 2; c++) {
        const int o = tid + c * 256;
        ((short8*)Al[s])[o] = ga[(size_t)s * s8A + o];
        ((short8*)Bl[s])[o] = gb[(size_t)s * s8B + o];
      }
    }
    __syncthreads();
    short8 af[3][4];
#pragma unroll
    for (int s = 0; s < 3; s++)
#pragma unroll
      for (int mi = 0; mi < 4; mi++)
        af[s][mi] = ((const short8*)Al[s])[(wr * 4 + mi) * 64 + lane];
    short8 bf[4];
#pragma unroll
    for (int ni = 0; ni < 4; ni++)
      bf[ni] = ((const short8*)Bl[0])[(wc * 4 + ni) * 64 + lane];
    MMTERM(0) MMTERM(1) MMTERM(2)
#pragma unroll
    for (int ni = 0; ni < 4; ni++)
      bf[ni] = ((const short8*)Bl[1])[(wc * 4 + ni) * 64 + lane];
    MMTERM(0) MMTERM(1)
#pragma unroll
    for (int ni = 0; ni < 4; ni++)
      bf[ni] = ((const short8*)Bl[2])[(wc * 4 + ni) * 64 + lane];
    MMTERM(0)
  }

  const int m0 = mb * 128 + wr * 64;
  const int n0c = nb * 128 + wc * 64 + (lane & 15);
  const int r0 = (lane >> 4) * 4;
#pragma unroll
  for (int mi = 0; mi < 4; mi++) {
#pragma unroll
    for (int ni = 0; ni < 4; ni++) {
      const int col = n0c + ni * 16;
      const float bb = bias ? bias[col] : 0.f;
      f32x4 a = acc[mi][ni];
#pragma unroll
      for (int r = 0; r < 4; r++)
        C[(size_t)(m0 + mi * 16 + r0 + r) * DD + col] = a[r] + bb;
    }
  }
}

// ------------- dense f32 GEMM NT: M = Wq @ Wk^T, 64x64 tile ------------------
struct GemmNT {
  const float *A0, *B0, *A1, *B1;
  float *C0, *C1;
};

__global__ __launch_bounds__(256) void k_gemm_nt(GemmNT p) {
  __shared__ __align__(16) float As[32][68];
  __shared__ __align__(16) float Bs[32][68];
  const int tid = threadIdx.x;
  const int mat = blockIdx.y >> 3;
  const int n0 = (blockIdx.y & 7) * 64;
  const int m0 = blockIdx.x * 64;
  const float* A = mat == 0 ? p.A0 : p.A1;
  const float* B = mat == 0 ? p.B0 : p.B1;
  float* C       = mat == 0 ? p.C0 : p.C1;
  const int tx = tid & 15, ty = tid >> 4;
  const int lr = tid >> 3, lc = (tid & 7) * 4;

  float4 fa[2], fb[2];
#pragma unroll
  for (int q = 0; q < 2; q++) {
    fa[q] = *(const float4*)(A + (size_t)(m0 + lr + 32 * q) * DD + lc);
    fb[q] = *(const float4*)(B + (size_t)(n0 + lr + 32 * q) * DD + lc);
  }
#pragma unroll
  for (int q = 0; q < 2; q++) {
    As[lc + 0][lr + 32 * q] = fa[q].x;
    As[lc + 1][lr + 32 * q] = fa[q].y;
    As[lc + 2][lr + 32 * q] = fa[q].z;
    As[lc + 3][lr + 32 * q] = fa[q].w;
    Bs[lc + 0][lr + 32 * q] = fb[q].x;
    Bs[lc + 1][lr + 32 * q] = fb[q].y;
    Bs[lc + 2][lr + 32 * q] = fb[q].z;
    Bs[lc + 3][lr + 32 * q] = fb[q].w;
  }
  __syncthreads();

  float acc[4][4];
#pragma unroll
  for (int i = 0; i < 4; i++)
#pragma unroll
    for (int j = 0; j < 4; j++) acc[i][j] = 0.f;

  for (int t = 0; t < 16; t++) {
    if (t < 15) {
      const int k0 = (t + 1) * 32;
#pragma unroll
      for (int q = 0; q < 2; q++) {
        fa[q] = *(const float4*)(A + (size_t)(m0 + lr + 32 * q) * DD + k0 + lc);
        fb[q] = *(const float4*)(B + (size_t)(n0 + lr + 32 * q) * DD + k0 + lc);
      }
    }
#pragma unroll
    for (int kk = 0; kk < 32; kk++) {
      float4 a = *(const float4*)&As[kk][ty * 4];
      float4 b = *(const float4*)&Bs[kk][tx * 4];
      float av[4] = {a.x, a.y, a.z, a.w};
      float bv[4] = {b.x, b.y, b.z, b.w};
#pragma unroll
      for (int i = 0; i < 4; i++)
#pragma unroll
        for (int j = 0; j < 4; j++) acc[i][j] = fmaf(av[i], bv[j], acc[i][j]);
    }
    __syncthreads();
    if (t < 15) {
#pragma unroll
      for (int q = 0; q < 2; q++) {
        As[lc + 0][lr + 32 * q] = fa[q].x;
        As[lc + 1][lr + 32 * q] = fa[q].y;
        As[lc + 2][lr + 32 * q] = fa[q].z;
        As[lc + 3][lr + 32 * q] = fa[q].w;
        Bs[lc + 0][lr + 32 * q] = fb[q].x;
        Bs[lc + 1][lr + 32 * q] = fb[q].y;
        Bs[lc + 2][lr + 32 * q] = fb[q].z;
        Bs[lc + 3][lr + 32 * q] = fb[q].w;
      }
      __syncthreads();
    }
  }

#pragma unroll
  for (int i = 0; i < 4; i++) {
    const int m = m0 + ty * 4 + i;
    float4 o = {acc[i][0], acc[i][1], acc[i][2], acc[i][3]};
    *(float4*)(C + (size_t)m * DD + n0 + tx * 4) = o;
  }
}

// ---- w1 = Wq@bk, w2 = Wk@bq, gamma = bq.bk (per layer) ----------------------
struct W12P {
  const float *Wq0, *bk0, *Wk0, *bq0;
  const float *Wq1, *bk1, *Wk1, *bq1;
  float *w10, *w20, *w11, *w21, *gam;
};

__global__ __launch_bounds__(256) void k_w12(W12P p) {
  const int l = blockIdx.y;
  const float* Wq = l ? p.Wq1 : p.Wq0;
  const float* bk = l ? p.bk1 : p.bk0;
  const float* Wk = l ? p.Wk1 : p.Wk0;
  const float* bq = l ? p.bq1 : p.bq0;
  float* w1 = l ? p.w11 : p.w10;
  float* w2 = l ? p.w21 : p.w20;
  const int wv = threadIdx.x >> 6, lane = threadIdx.x & 63;
  const int r = blockIdx.x * 4 + wv;
  float s1 = 0.f, s2 = 0.f;
  for (int k = lane; k < DD; k += 64) {
    s1 = fmaf(Wq[(size_t)r * DD + k], bk[k], s1);
    s2 = fmaf(Wk[(size_t)r * DD + k], bq[k], s2);
  }
#pragma unroll
  for (int off = 32; off > 0; off >>= 1) {
    s1 += __shfl_xor(s1, off);
    s2 += __shfl_xor(s2, off);
  }
  if (lane == 0) { w1[r] = s1; w2[r] = s2; }
  if (blockIdx.x == 0 && wv == 0) {
    float g = 0.f;
    for (int k = lane; k < DD; k += 64) g = fmaf(bq[k], bk[k], g);
#pragma unroll
    for (int off = 32; off > 0; off >>= 1) g += __shfl_xor(g, off);
    if (lane == 0) p.gam[l] = g;
  }
}

// ---- alpha_l = U_l @ w1_l, beta_l = U_l @ w2_l ------------------------------
struct AbP {
  const float *U1, *U2, *w10, *w20, *w11, *w21;
  float *a1, *b1, *a2, *b2;
};

__global__ __launch_bounds__(256) void k_ab(AbP p) {
  const int wv = threadIdx.x >> 6, lane = threadIdx.x & 63;
  const int r = blockIdx.x * 4 + wv;
  const int base = lane * 8;
  float4 wa0 = *(const float4*)(p.w10 + base);
  float4 wa1 = *(const float4*)(p.w10 + base + 4);
  float4 wb0 = *(const float4*)(p.w20 + base);
  float4 wb1 = *(const float4*)(p.w20 + base + 4);
  float4 u0 = *(const float4*)(p.U1 + (size_t)r * DD + base);
  float4 u1 = *(const float4*)(p.U1 + (size_t)r * DD + base + 4);
  float sa = u0.x * wa0.x + u0.y * wa0.y + u0.z * wa0.z + u0.w * wa0.w +
             u1.x * wa1.x + u1.y * wa1.y + u1.z * wa1.z + u1.w * wa1.w;
  float sb = u0.x * wb0.x + u0.y * wb0.y + u0.z * wb0.z + u0.w * wb0.w +
             u1.x * wb1.x + u1.y * wb1.y + u1.z * wb1.z + u1.w * wb1.w;
#pragma unroll
  for (int off = 32; off > 0; off >>= 1) {
    sa += __shfl_xor(sa, off);
    sb += __shfl_xor(sb, off);
  }
  if (lane == 0) { p.a1[r] = sa; p.b1[r] = sb; }
  wa0 = *(const float4*)(p.w11 + base);
  wa1 = *(const float4*)(p.w11 + base + 4);
  wb0 = *(const float4*)(p.w21 + base);
  wb1 = *(const float4*)(p.w21 + base + 4);
  u0 = *(const float4*)(p.U2 + (size_t)r * DD + base);
  u1 = *(const float4*)(p.U2 + (size_t)r * DD + base + 4);
  sa = u0.x * wa0.x + u0.y * wa0.y + u0.z * wa0.z + u0.w * wa0.w +
       u1.x * wa1.x + u1.y * wa1.y + u1.z * wa1.z + u1.w * wa1.w;
  sb = u0.x * wb0.x + u0.y * wb0.y + u0.z * wb0.z + u0.w * wb0.w +
       u1.x * wb1.x + u1.y * wb1.y + u1.z * wb1.z + u1.w * wb1.w;
#pragma unroll
  for (int off = 32; off > 0; off >>= 1) {
    sa += __shfl_xor(sa, off);
    sb += __shfl_xor(sb, off);
  }
  if (lane == 0) { p.a2[r] = sa; p.b2[r] = sb; }
}

// ---- SDDMM + softmax + dense scatter for ONE layer (lfix) -------------------
struct ScP {
  const int *cols, *cnts;
  const float *V, *U, *al, *be;
  const float* gam;
  const int* degA;
  float *av, *dense;   // dense != nullptr only for layer 1
  int lfix;
};

__global__ __launch_bounds__(256) void k_score(ScP p) {
  const int* cols = p.cols;
  const int* cnts = p.cnts;
  const float* V = p.V;
  const float* U = p.U;
  float* dense = p.dense;
  const int r = blockIdx.x;
  const int t = threadIdx.x;
  const int lane = t & 63, wv = t >> 6;
  const int cnt = cnts[r];
  __shared__ int scol[ELL];
  __shared__ float ssc[ELL];
  if (t < ELL) scol[t] = (t < cnt) ? cols[(size_t)r * ELL + t] : 0;
  if (dense) {
    float4 z = {0.f, 0.f, 0.f, 0.f};
    float4* drow = (float4*)(dense + (size_t)r * NN);
#pragma unroll
    for (int q = 0; q < 4; q++) drow[t + 256 * q] = z;
  }
  __syncthreads();
  const float g = p.gam[p.lfix];
  const float dr = (float)p.degA[r];
  const float ar = p.al[r];
  const float* Vr = V + (size_t)r * DD + lane * 8;
  float4 q0 = *(const float4*)Vr;
  float4 q1 = *(const float4*)(Vr + 4);
  for (int k = wv; k < cnt; k += 4) {
    const int c = scol[k];
    const float* Uc = U + (size_t)c * DD + lane * 8;
    float4 k0 = *(const float4*)Uc;
    float4 k1 = *(const float4*)(Uc + 4);
    float s = q0.x * k0.x + q0.y * k0.y + q0.z * k0.z + q0.w * k0.w +
              q1.x * k1.x + q1.y * k1.y + q1.z * k1.z + q1.w * k1.w;
#pragma unroll
    for (int off = 32; off > 0; off >>= 1) s += __shfl_xor(s, off);
    if (lane == 0) {
      const float dc = (float)p.degA[c];
      ssc[k] = s + dc * ar + dr * p.be[c] + dr * dc * g;
    }
  }
  __syncthreads();
  if (wv == 0) {
    float v0 = (lane < cnt) ? ssc[lane] : -INFINITY;
    float v1 = (lane + 64 < cnt) ? ssc[lane + 64] : -INFINITY;
    float mx = fmaxf(v0, v1);
#pragma unroll
    for (int off = 32; off > 0; off >>= 1) mx = fmaxf(mx, __shfl_xor(mx, off));
    float e0 = (lane < cnt) ? expf(v0 - mx) : 0.f;
    float e1 = (lane + 64 < cnt) ? expf(v1 - mx) : 0.f;
    float sm = e0 + e1;
#pragma unroll
    for (int off = 32; off > 0; off >>= 1) sm += __shfl_xor(sm, off);
    float inv = 1.f / sm;
    if (lane < cnt) ssc[lane] = e0 * inv;
    if (lane + 64 < cnt) ssc[lane + 64] = e1 * inv;
  }
  __syncthreads();
  if (t < cnt) {
    const float v = ssc[t];
    p.av[(size_t)r * ELL + t] = v;
    if (dense) dense[(size_t)r * NN + scol[t]] = v;
  }
}

// ---- panel PV: out[r, pan] = sum_k att_k * Tb[c_k, pan] (bf16, 1MB panels) --
struct PvP {
  const int *cols0, *cnts0, *cols1, *cnts1;
  const float *av0, *av1;
  const unsigned short *T0, *T1;
  float *out0, *out1;
};

__global__ __launch_bounds__(256) void k_pv_pan(PvP p) {
  const int bid = blockIdx.x;
  const int rgrp = bid & (NN / 4 - 1);
  const int g = bid / (NN / 4);
  const int pan = g & 3, l = g >> 2;
  const int* cols = l ? p.cols1 : p.cols0;
  const int* cnts = l ? p.cnts1 : p.cnts0;
  const float* av = l ? p.av1 : p.av0;
  const unsigned short* Tb = l ? p.T1 : p.T0;
  float* out = l ? p.out1 : p.out0;
  const int wv = threadIdx.x >> 6, lane = threadIdx.x & 63;
  const int row = rgrp * 4 + wv;
  __shared__ int scol[4][ELL];
  __shared__ float sval[4][ELL];
  const int cnt = cnts[row];
  for (int i = lane; i < ELL; i += 64) {
    scol[wv][i] = (i < cnt) ? cols[(size_t)row * ELL + i] : 0;
    sval[wv][i] = (i < cnt) ? av[(size_t)row * ELL + i] : 0.f;
  }
  const int cb = pan * 128 + lane * 2;
  float a0 = 0.f, a1 = 0.f;
#pragma unroll 4
  for (int k = 0; k < cnt; k++) {
    const float v = sval[wv][k];
    const unsigned u = *(const unsigned*)(Tb + (size_t)scol[wv][k] * DD + cb);
    a0 = fmaf(v, __uint_as_float(u << 16), a0);
    a1 = fmaf(v, __uint_as_float(u & 0xffff0000u), a1);
  }
  float2 o = {a0, a1};
  *(float2*)(out + (size_t)row * DD + cb) = o;
}

// ---- panel structural SpMM: C[r, pan] = sum_c B[c, pan] ---------------------
struct SpF {
  const int *colsA, *cntsA, *colsB, *cntsB;
  const float *BA, *BB;
  float *CA, *CB;
};

__global__ __launch_bounds__(256) void k_spmm_pan(SpF p) {
  const int bid = blockIdx.x;
  const int rgrp = bid & (NN / 4 - 1);
  const int g = bid / (NN / 4);
  const int pan = g & 3, mat = g >> 2;
  const int* cols = mat ? p.colsB : p.colsA;
  const int* cnts = mat ? p.cntsB : p.cntsA;
  const float* B = mat ? p.BB : p.BA;
  float* C = mat ? p.CB : p.CA;
  const int wv = threadIdx.x >> 6, lane = threadIdx.x & 63;
  const int row = rgrp * 4 + wv;
  __shared__ int scol[4][ELL];
  const int cnt = cnts[row];
  for (int i = lane; i < ELL; i += 64)
    scol[wv][i] = (i < cnt) ? cols[(size_t)row * ELL + i] : 0;
  const int cb = pan * 128 + lane * 2;
  float2 acc = {0.f, 0.f};
#pragma unroll 4
  for (int k = 0; k < cnt; k++) {
    const float2 b = *(const float2*)(B + (size_t)scol[wv][k] * DD + cb);
    acc.x += b.x;
    acc.y += b.y;
  }
  *(float2*)(C + (size_t)row * DD + cb) = acc;
}

// -------- fused: row-normalize 3 segments + mask + relu + classifier + lsm ---
__global__ __launch_bounds__(256) void k_norm_cls(const float* __restrict__ T0,
                                                  const float* __restrict__ T1,
                                                  const float* __restrict__ T2,
                                                  const float* __restrict__ hop,
                                                  const float* __restrict__ Wc,
                                                  const float* __restrict__ bc,
                                                  float* __restrict__ out) {
  const int r = blockIdx.x;
  const int t = threadIdx.x;
  const int lane = t & 63, wv = t >> 6;
  __shared__ __align__(16) float srow[1536];
  __shared__ float red[4];
  __shared__ float pr[6][40];
  float h0 = hop[0], h1 = hop[1], h2 = hop[2];
  float hm = fmaxf(h0, fmaxf(h1, h2));
  float e0 = expf(h0 - hm), e1 = expf(h1 - hm), e2 = expf(h2 - hm);
  float minv = 1.f / (e0 + e1 + e2);
  float mask[3] = {e0 * minv, e1 * minv, e2 * minv};
  const float* Ts[3] = {T0, T1, T2};
#pragma unroll
  for (int s = 0; s < 3; s++) {
    float x0 = Ts[s][(size_t)r * DD + t];
    float x1 = Ts[s][(size_t)r * DD + t + 256];
    float ss = x0 * x0 + x1 * x1;
#pragma unroll
    for (int off = 32; off > 0; off >>= 1) ss += __shfl_xor(ss, off);
    if (lane == 0) red[wv] = ss;
    __syncthreads();
    float tot = red[0] + red[1] + red[2] + red[3];
    float nrm = fmaxf(sqrtf(tot), 1e-12f);
    float sc = mask[s] / nrm;
    srow[s * DD + t] = fmaxf(x0 * sc, 0.f);
    srow[s * DD + t + 256] = fmaxf(x1 * sc, 0.f);
    __syncthreads();
  }
  float part = 0.f;
  const int col = t % 40, seg = t / 40;
  if (seg < 6) {
    const float* w = Wc + col;
#pragma unroll 4
    for (int k = seg * 256; k < seg * 256 + 256; k++)
      part = fmaf(srow[k], w[(size_t)k * 40], part);
    pr[seg][col] = part;
  }
  __syncthreads();
  if (t < 64) {
    float lg = -INFINITY;
    if (t < 40) {
      lg = bc[t];
#pragma unroll
      for (int s6 = 0; s6 < 6; s6++) lg += pr[s6][t];
    }
    float mx = lg;
#pragma unroll
    for (int off = 32; off > 0; off >>= 1) mx = fmaxf(mx, __shfl_xor(mx, off));
    float ex = (t < 40) ? expf(lg - mx) : 0.f;
    float sm = ex;
#pragma unroll
    for (int off = 32; off > 0; off >>= 1) sm += __shfl_xor(sm, off);
    float ls = logf(sm);
    if (t < 40) out[(size_t)r * 40 + t] = lg - mx - ls;
  }
}

extern "C" void kernel_launch(void* const* d_in, const int* in_sizes, int n_in,
                              void* d_out, int out_size, void* d_ws, size_t ws_size,
                              hipStream_t stream) {
  (void)in_sizes; (void)n_in; (void)out_size; (void)ws_size;
  const float* x    = (const float*)d_in[0];
  const float* adjA = (const float*)d_in[1];
  const float* adj1 = (const float*)d_in[2];
  const float* adj2 = (const float*)d_in[3];
  const float* hop  = (const float*)d_in[4];
  const float* Wfc0 = (const float*)d_in[5];  const float* bfc0 = (const float*)d_in[6];
  const float* Wfc1 = (const float*)d_in[7];  const float* bfc1 = (const float*)d_in[8];
  const float* Wfc2 = (const float*)d_in[9];  const float* bfc2 = (const float*)d_in[10];
  const float* Wq0  = (const float*)d_in[11]; const float* bq0  = (const float*)d_in[12];
  const float* Wk0  = (const float*)d_in[13]; const float* bk0  = (const float*)d_in[14];
  const float* Wq1  = (const float*)d_in[15]; const float* bq1  = (const float*)d_in[16];
  const float* Wk1  = (const float*)d_in[17]; const float* bk1  = (const float*)d_in[18];
  const float* Wc   = (const float*)d_in[19]; const float* bc   = (const float*)d_in[20];

  float* ws = (float*)d_ws;
  const size_t MD = (size_t)NN * DD;
  const size_t WD = (size_t)DD * DD;
  float* TMP0 = ws + 0 * MD;
  float* TMP1 = ws + 1 * MD;   // f32 tmp1; dead after spmm s1 -> reused as ATTV1
  float* TMP2 = ws + 2 * MD;   // f32 tmp2; dead after spmm s1 -> reused as ATTV2
  float* S3   = ws + 3 * MD;   // t_att1 -> V1 -> out1
  float* S4   = ws + 4 * MD;   // t_att2 -> V2 -> out2
  float* U1   = ws + 5 * MD;
  float* U2   = ws + 6 * MD;
  float* M1   = ws + 7 * MD;
  float* M2   = M1 + WD;
  float* w10 = M2 + WD;
  float* w20 = w10 + DD;
  float* w11 = w20 + DD;
  float* w21 = w11 + DD;
  float* gam = w21 + DD;
  float* AL1 = gam + 4;
  float* BE1 = AL1 + NN;
  float* AL2 = BE1 + NN;
  float* BE2 = AL2 + NN;
  int* ELLA = (int*)(BE2 + NN);
  int* ELL1 = ELLA + (size_t)NN * ELL;
  int* ELL2 = ELL1 + (size_t)NN * ELL;
  int* CNTA = ELL2 + (size_t)NN * ELL;
  int* CNT1 = CNTA + NN;
  int* CNT2 = CNT1 + NN;
  unsigned short* Tb1 = (unsigned short*)(CNT2 + NN);  // bf16 TMP1 (4 MB)
  unsigned short* Tb2 = Tb1 + MD;                      // bf16 TMP2 (4 MB)
  float* ATTV1 = TMP1;   // reuse: TMP1 f32 dead after spmm s1
  float* ATTV2 = TMP2;

  float* outLog = (float*)d_out;
  float* outAtt = outLog + (size_t)NN * 40;
  unsigned short* xb   = (unsigned short*)outAtt;
  unsigned short* wfcb = xb + 3 * MD;
  unsigned short* Ub1  = wfcb + 9 * WD;
  unsigned short* Ub2  = Ub1 + 3 * MD;
  unsigned short* Mb1  = Ub2 + 3 * MD;
  unsigned short* Mb2  = Mb1 + 3 * WD;

  Build3 pb{adjA, adj1, adj2, ELLA, ELL1, ELL2, CNTA, CNT1, CNT2};
  k_build3<<<dim3(NN / 4, 3), 256, 0, stream>>>(pb);

  W12P pw{Wq0, bk0, Wk0, bq0, Wq1, bk1, Wk1, bq1, w10, w20, w11, w21, gam};
  k_w12<<<dim3(DD / 4, 2), 256, 0, stream>>>(pw);

  Split4 sp1{{{x, xb, NN, 0},
              {Wfc0, wfcb + 0 * 3 * WD, DD, 1},
              {Wfc1, wfcb + 1 * 3 * WD, DD, 1},
              {Wfc2, wfcb + 2 * 3 * WD, DD, 1}}};
  k_split<<<dim3(1024, 4), 256, 0, stream>>>(sp1);

  GmP pf{xb, xb, xb,
         wfcb + 0 * 3 * WD, wfcb + 1 * 3 * WD, wfcb + 2 * 3 * WD,
         bfc0, bfc1, bfc2, TMP0, TMP1, TMP2, MD, WD};
  k_gemm_mfma<<<dim3(32, 12), 256, 0, stream>>>(pf);

  GemmNT pm{Wq0, Wk0, Wq1, Wk1, M1, M2};
  k_gemm_nt<<<dim3(8, 16), 256, 0, stream>>>(pm);

  // bf16 copies of tmp1/tmp2 for the PV gather
  ToBf tb{TMP1, TMP2, Tb1, Tb2};
  k_tobf16<<<dim3(1024, 2), 256, 0, stream>>>(tb);

  // t_att_l = adjA @ tmp_l ; U_l = adjA @ t_att_l  (panel-temporal ordering)
  SpF s1{ELLA, CNTA, ELLA, CNTA, TMP1, TMP2, S3, S4};
  k_spmm_pan<<<8 * (NN / 4), 256, 0, stream>>>(s1);
  SpF s2{ELLA, CNTA, ELLA, CNTA, S3, S4, U1, U2};
  k_spmm_pan<<<8 * (NN / 4), 256, 0, stream>>>(s2);

  Split4 sp2{{{U1, Ub1, NN, 0},
              {U2, Ub2, NN, 0},
              {M1, Mb1, DD, 1},
              {M2, Mb2, DD, 1}}};
  k_split<<<dim3(1024, 4), 256, 0, stream>>>(sp2);

  GmP pv{Ub1, Ub2, nullptr, Mb1, Mb2, nullptr,
         nullptr, nullptr, nullptr, S3, S4, nullptr, MD, WD};
  k_gemm_mfma<<<dim3(32, 8), 256, 0, stream>>>(pv);

  AbP pab{U1, U2, w10, w20, w11, w21, AL1, BE1, AL2, BE2};
  k_ab<<<NN / 4, 256, 0, stream>>>(pab);

  // phase 1: per-layer score dispatches (halved concurrent gather working set)
  ScP sc0{ELL1, CNT1, S3, U1, AL1, BE1, gam, CNTA, ATTV1, nullptr, 0};
  k_score<<<NN, 256, 0, stream>>>(sc0);
  ScP sc1{ELL2, CNT2, S4, U2, AL2, BE2, gam, CNTA, ATTV2, outAtt, 1};
  k_score<<<NN, 256, 0, stream>>>(sc1);

  // phase 2: panel PV gather over bf16 tmp (1 MB concurrent working set)
  PvP pp{ELL1, CNT1, ELL2, CNT2, ATTV1, ATTV2, Tb1, Tb2, S3, S4};
  k_pv_pan<<<8 * (NN / 4), 256, 0, stream>>>(pp);

  k_norm_cls<<<NN, 256, 0, stream>>>(TMP0, S3, S4, hop, Wc, bc, outLog);
}

// Round 15
// 423.050 us; speedup vs baseline: 1.0214x; 1.0214x over previous
//
#include <hip/hip_runtime.h>
#include <math.h>

#define NN 4096
#define DD 512
#define ELL 128

typedef unsigned long long u64;
typedef __attribute__((ext_vector_type(8))) short short8;
typedef __attribute__((ext_vector_type(8))) unsigned short ushort8;
typedef __attribute__((ext_vector_type(4))) float f32x4;

static __device__ __forceinline__ unsigned short f2bf(float f) {
  unsigned u = __float_as_uint(f);
  unsigned r = (u + 0x7fffu + ((u >> 16) & 1u)) >> 16;
  return (unsigned short)r;
}
static __device__ __forceinline__ float bf2f(unsigned short h) {
  return __uint_as_float(((unsigned)h) << 16);
}

// ---------------- build ELL: block/row, mask + block-wide exclusive scan -----
struct Build3 {
  const float *adj0, *adj1, *adj2;
  int *c0, *c1, *c2;
  int *n0, *n1, *n2;
};

__global__ __launch_bounds__(256) void k_build3(Build3 p) {
  const int s = blockIdx.y;
  const float* adj = s == 0 ? p.adj0 : (s == 1 ? p.adj1 : p.adj2);
  int* cols = s == 0 ? p.c0 : (s == 1 ? p.c1 : p.c2);
  int* cnt  = s == 0 ? p.n0 : (s == 1 ? p.n1 : p.n2);
  const int r = blockIdx.x;
  const int t = threadIdx.x;
  const int lane = t & 63, wv = t >> 6;
  const float* row = adj + (size_t)r * NN + t * 16;
  int* rc = cols + (size_t)r * ELL;

  float4 v0 = *(const float4*)(row + 0);
  float4 v1 = *(const float4*)(row + 4);
  float4 v2 = *(const float4*)(row + 8);
  float4 v3 = *(const float4*)(row + 12);
  unsigned mask = 0;
  mask |= (v0.x > 0.f) << 0;  mask |= (v0.y > 0.f) << 1;
  mask |= (v0.z > 0.f) << 2;  mask |= (v0.w > 0.f) << 3;
  mask |= (v1.x > 0.f) << 4;  mask |= (v1.y > 0.f) << 5;
  mask |= (v1.z > 0.f) << 6;  mask |= (v1.w > 0.f) << 7;
  mask |= (v2.x > 0.f) << 8;  mask |= (v2.y > 0.f) << 9;
  mask |= (v2.z > 0.f) << 10; mask |= (v2.w > 0.f) << 11;
  mask |= (v3.x > 0.f) << 12; mask |= (v3.y > 0.f) << 13;
  mask |= (v3.z > 0.f) << 14; mask |= (v3.w > 0.f) << 15;
  const int mycnt = __popc(mask);

  int incl = mycnt;
#pragma unroll
  for (int off = 1; off < 64; off <<= 1) {
    int n = __shfl_up(incl, off);
    if (lane >= off) incl += n;
  }
  __shared__ int wsum[4];
  if (lane == 63) wsum[wv] = incl;
  __syncthreads();
  int base = 0;
#pragma unroll
  for (int w = 0; w < 4; w++)
    if (w < wv) base += wsum[w];
  int off = base + incl - mycnt;
  unsigned m = mask;
  while (m) {
    const int b = __ffs(m) - 1;
    if (off < ELL) rc[off] = t * 16 + b;
    off++;
    m &= m - 1;
  }
  if (t == 255) {
    const int tot = base + incl;
    cnt[r] = tot < ELL ? tot : ELL;
  }
}

// ---- split f32 matrix into 3 bf16 matrices in MFMA-fragment tile order ------
struct SplitE { const float* src; unsigned short* dst; int rows; int bstyle; };
struct Split4 { SplitE e[4]; };

__global__ __launch_bounds__(256) void k_split(Split4 p) {
  SplitE e = p.e[blockIdx.y];
  if (!e.src) return;
  const int oct = blockIdx.x * 256 + threadIdx.x;
  if (oct >= e.rows * 64) return;
  float v[8];
  size_t toff;
  if (!e.bstyle) {
    const int m = oct >> 6, kg = oct & 63;
    const float* sp = e.src + (size_t)m * 512 + kg * 8;
    float4 u0 = *(const float4*)sp;
    float4 u1 = *(const float4*)(sp + 4);
    v[0] = u0.x; v[1] = u0.y; v[2] = u0.z; v[3] = u0.w;
    v[4] = u1.x; v[5] = u1.y; v[6] = u1.z; v[7] = u1.w;
    toff = ((size_t)(m >> 7) * 16 + (kg >> 2)) * 4096 +
           (size_t)((m & 127) >> 4) * 512 + (size_t)(kg & 3) * 128 +
           (size_t)(m & 15) * 8;
  } else {
    const int n = oct & 511, kog = oct >> 9;
    const int k0 = kog * 8;
#pragma unroll
    for (int i = 0; i < 8; i++) v[i] = e.src[(size_t)(k0 + i) * 512 + n];
    toff = ((size_t)(n >> 7) * 16 + (kog >> 2)) * 4096 +
           (size_t)((n & 127) >> 4) * 512 + (size_t)(kog & 3) * 128 +
           (size_t)(n & 15) * 8;
  }
  ushort8 h0, h1, h2;
#pragma unroll
  for (int i = 0; i < 8; i++) {
    float f = v[i];
    unsigned short a0 = f2bf(f);
    float r1 = f - bf2f(a0);
    unsigned short a1 = f2bf(r1);
    float r2 = r1 - bf2f(a1);
    unsigned short a2 = f2bf(r2);
    h0[i] = a0; h1[i] = a1; h2[i] = a2;
  }
  const size_t stride = (size_t)e.rows * 512;
  *(ushort8*)(e.dst + toff) = h0;
  *(ushort8*)(e.dst + stride + toff) = h1;
  *(ushort8*)(e.dst + 2 * stride + toff) = h2;
}

// ---- plain f32 -> bf16 row-major copy (for PV gather) -----------------------
struct ToBf {
  const float *s0, *s1;
  unsigned short *d0, *d1;
};

__global__ __launch_bounds__(256) void k_tobf16(ToBf p) {
  const float* s = blockIdx.y ? p.s1 : p.s0;
  unsigned short* d = blockIdx.y ? p.d1 : p.d0;
  const size_t i = ((size_t)blockIdx.x * 256 + threadIdx.x) * 8;
  float4 a = *(const float4*)(s + i);
  float4 b = *(const float4*)(s + i + 4);
  ushort8 h;
  h[0] = f2bf(a.x); h[1] = f2bf(a.y); h[2] = f2bf(a.z); h[3] = f2bf(a.w);
  h[4] = f2bf(b.x); h[5] = f2bf(b.y); h[6] = f2bf(b.z); h[7] = f2bf(b.w);
  *(ushort8*)(d + i) = h;
}

// ---- MFMA GEMM: C[rows x 512] = A @ B (+bias), exact via 3-way bf16 split ---
struct GmP {
  const unsigned short *A0, *A1, *A2;
  const unsigned short *B0, *B1, *B2;
  const float *b0, *b1, *b2;
  float *C0, *C1, *C2;
  size_t sA, sB;
};

#define MMTERM(sa)                                                          \
  _Pragma("unroll")                                                         \
  for (int mi = 0; mi < 4; mi++) {                                          \
    _Pragma("unroll")                                                       \
    for (int ni = 0; ni < 4; ni++)                                          \
      acc[mi][ni] = __builtin_amdgcn_mfma_f32_16x16x32_bf16(                \
          af[sa][mi], bf[ni], acc[mi][ni], 0, 0, 0);                        \
  }

__global__ __launch_bounds__(256) void k_gemm_mfma(GmP p) {
  __shared__ __align__(16) unsigned short Al[3][4096];
  __shared__ __align__(16) unsigned short Bl[3][4096];
  const int tid = threadIdx.x;
  const int mat = blockIdx.y >> 2;
  const int nb = blockIdx.y & 3;
  const int mb = blockIdx.x;
  const unsigned short* A = mat == 0 ? p.A0 : (mat == 1 ? p.A1 : p.A2);
  const unsigned short* B = mat == 0 ? p.B0 : (mat == 1 ? p.B1 : p.B2);
  const float* bias = mat == 0 ? p.b0 : (mat == 1 ? p.b1 : p.b2);
  float* C = mat == 0 ? p.C0 : (mat == 1 ? p.C1 : p.C2);
  const int lane = tid & 63, w = tid >> 6, wr = w >> 1, wc = w & 1;
  const size_t s8A = p.sA >> 3, s8B = p.sB >> 3;

  f32x4 acc[4][4];
#pragma unroll
  for (int mi = 0; mi < 4; mi++)
#pragma unroll
    for (int ni = 0; ni < 4; ni++) acc[mi][ni] = (f32x4){0.f, 0.f, 0.f, 0.f};

  for (int kb = 0; kb < 16; kb++) {
    const short8* ga = (const short8*)(A + ((size_t)mb * 16 + kb) * 4096);
    const short8* gb = (const short8*)(B + ((size_t)nb * 16 + kb) * 4096);
    __syncthreads();
#pragma unroll
    for (int s = 0; s < 3; s++) {
#pragma unroll
      for (int c = 0; c < 2; c++) {
        const int o = tid + c * 256;
        ((short8*)Al[s])[o] = ga[(size_t)s * s8A + o];
        ((short8*)Bl[s])[o] = gb[(size_t)s * s8B + o];
      }
    }
    __syncthreads();
    short8 af[3][4];
#pragma unroll
    for (int s = 0; s < 3; s++)
#pragma unroll
      for (int mi = 0; mi < 4; mi++)
        af[s][mi] = ((const short8*)Al[s])[(wr * 4 + mi) * 64 + lane];
    short8 bf[4];
#pragma unroll
    for (int ni = 0; ni < 4; ni++)
      bf[ni] = ((const short8*)Bl[0])[(wc * 4 + ni) * 64 + lane];
    MMTERM(0) MMTERM(1) MMTERM(2)
#pragma unroll
    for (int ni = 0; ni < 4; ni++)
      bf[ni] = ((const short8*)Bl[1])[(wc * 4 + ni) * 64 + lane];
    MMTERM(0) MMTERM(1)
#pragma unroll
    for (int ni = 0; ni < 4; ni++)
      bf[ni] = ((const short8*)Bl[2])[(wc * 4 + ni) * 64 + lane];
    MMTERM(0)
  }

  const int m0 = mb * 128 + wr * 64;
  const int n0c = nb * 128 + wc * 64 + (lane & 15);
  const int r0 = (lane >> 4) * 4;
#pragma unroll
  for (int mi = 0; mi < 4; mi++) {
#pragma unroll
    for (int ni = 0; ni < 4; ni++) {
      const int col = n0c + ni * 16;
      const float bb = bias ? bias[col] : 0.f;
      f32x4 a = acc[mi][ni];
#pragma unroll
      for (int r = 0; r < 4; r++)
        C[(size_t)(m0 + mi * 16 + r0 + r) * DD + col] = a[r] + bb;
    }
  }
}

// ------------- dense f32 GEMM NT: M = Wq @ Wk^T, 64x64 tile ------------------
struct GemmNT {
  const float *A0, *B0, *A1, *B1;
  float *C0, *C1;
};

__global__ __launch_bounds__(256) void k_gemm_nt(GemmNT p) {
  __shared__ __align__(16) float As[32][68];
  __shared__ __align__(16) float Bs[32][68];
  const int tid = threadIdx.x;
  const int mat = blockIdx.y >> 3;
  const int n0 = (blockIdx.y & 7) * 64;
  const int m0 = blockIdx.x * 64;
  const float* A = mat == 0 ? p.A0 : p.A1;
  const float* B = mat == 0 ? p.B0 : p.B1;
  float* C       = mat == 0 ? p.C0 : p.C1;
  const int tx = tid & 15, ty = tid >> 4;
  const int lr = tid >> 3, lc = (tid & 7) * 4;

  float4 fa[2], fb[2];
#pragma unroll
  for (int q = 0; q < 2; q++) {
    fa[q] = *(const float4*)(A + (size_t)(m0 + lr + 32 * q) * DD + lc);
    fb[q] = *(const float4*)(B + (size_t)(n0 + lr + 32 * q) * DD + lc);
  }
#pragma unroll
  for (int q = 0; q < 2; q++) {
    As[lc + 0][lr + 32 * q] = fa[q].x;
    As[lc + 1][lr + 32 * q] = fa[q].y;
    As[lc + 2][lr + 32 * q] = fa[q].z;
    As[lc + 3][lr + 32 * q] = fa[q].w;
    Bs[lc + 0][lr + 32 * q] = fb[q].x;
    Bs[lc + 1][lr + 32 * q] = fb[q].y;
    Bs[lc + 2][lr + 32 * q] = fb[q].z;
    Bs[lc + 3][lr + 32 * q] = fb[q].w;
  }
  __syncthreads();

  float acc[4][4];
#pragma unroll
  for (int i = 0; i < 4; i++)
#pragma unroll
    for (int j = 0; j < 4; j++) acc[i][j] = 0.f;

  for (int t = 0; t < 16; t++) {
    if (t < 15) {
      const int k0 = (t + 1) * 32;
#pragma unroll
      for (int q = 0; q < 2; q++) {
        fa[q] = *(const float4*)(A + (size_t)(m0 + lr + 32 * q) * DD + k0 + lc);
        fb[q] = *(const float4*)(B + (size_t)(n0 + lr + 32 * q) * DD + k0 + lc);
      }
    }
#pragma unroll
    for (int kk = 0; kk < 32; kk++) {
      float4 a = *(const float4*)&As[kk][ty * 4];
      float4 b = *(const float4*)&Bs[kk][tx * 4];
      float av[4] = {a.x, a.y, a.z, a.w};
      float bv[4] = {b.x, b.y, b.z, b.w};
#pragma unroll
      for (int i = 0; i < 4; i++)
#pragma unroll
        for (int j = 0; j < 4; j++) acc[i][j] = fmaf(av[i], bv[j], acc[i][j]);
    }
    __syncthreads();
    if (t < 15) {
#pragma unroll
      for (int q = 0; q < 2; q++) {
        As[lc + 0][lr + 32 * q] = fa[q].x;
        As[lc + 1][lr + 32 * q] = fa[q].y;
        As[lc + 2][lr + 32 * q] = fa[q].z;
        As[lc + 3][lr + 32 * q] = fa[q].w;
        Bs[lc + 0][lr + 32 * q] = fb[q].x;
        Bs[lc + 1][lr + 32 * q] = fb[q].y;
        Bs[lc + 2][lr + 32 * q] = fb[q].z;
        Bs[lc + 3][lr + 32 * q] = fb[q].w;
      }
      __syncthreads();
    }
  }

#pragma unroll
  for (int i = 0; i < 4; i++) {
    const int m = m0 + ty * 4 + i;
    float4 o = {acc[i][0], acc[i][1], acc[i][2], acc[i][3]};
    *(float4*)(C + (size_t)m * DD + n0 + tx * 4) = o;
  }
}

// ---- w1 = Wq@bk, w2 = Wk@bq, gamma = bq.bk (per layer) ----------------------
struct W12P {
  const float *Wq0, *bk0, *Wk0, *bq0;
  const float *Wq1, *bk1, *Wk1, *bq1;
  float *w10, *w20, *w11, *w21, *gam;
};

__global__ __launch_bounds__(256) void k_w12(W12P p) {
  const int l = blockIdx.y;
  const float* Wq = l ? p.Wq1 : p.Wq0;
  const float* bk = l ? p.bk1 : p.bk0;
  const float* Wk = l ? p.Wk1 : p.Wk0;
  const float* bq = l ? p.bq1 : p.bq0;
  float* w1 = l ? p.w11 : p.w10;
  float* w2 = l ? p.w21 : p.w20;
  const int wv = threadIdx.x >> 6, lane = threadIdx.x & 63;
  const int r = blockIdx.x * 4 + wv;
  float s1 = 0.f, s2 = 0.f;
  for (int k = lane; k < DD; k += 64) {
    s1 = fmaf(Wq[(size_t)r * DD + k], bk[k], s1);
    s2 = fmaf(Wk[(size_t)r * DD + k], bq[k], s2);
  }
#pragma unroll
  for (int off = 32; off > 0; off >>= 1) {
    s1 += __shfl_xor(s1, off);
    s2 += __shfl_xor(s2, off);
  }
  if (lane == 0) { w1[r] = s1; w2[r] = s2; }
  if (blockIdx.x == 0 && wv == 0) {
    float g = 0.f;
    for (int k = lane; k < DD; k += 64) g = fmaf(bq[k], bk[k], g);
#pragma unroll
    for (int off = 32; off > 0; off >>= 1) g += __shfl_xor(g, off);
    if (lane == 0) p.gam[l] = g;
  }
}

// ---- alpha_l = U_l @ w1_l, beta_l = U_l @ w2_l ------------------------------
struct AbP {
  const float *U1, *U2, *w10, *w20, *w11, *w21;
  float *a1, *b1, *a2, *b2;
};

__global__ __launch_bounds__(256) void k_ab(AbP p) {
  const int wv = threadIdx.x >> 6, lane = threadIdx.x & 63;
  const int r = blockIdx.x * 4 + wv;
  const int base = lane * 8;
  float4 wa0 = *(const float4*)(p.w10 + base);
  float4 wa1 = *(const float4*)(p.w10 + base + 4);
  float4 wb0 = *(const float4*)(p.w20 + base);
  float4 wb1 = *(const float4*)(p.w20 + base + 4);
  float4 u0 = *(const float4*)(p.U1 + (size_t)r * DD + base);
  float4 u1 = *(const float4*)(p.U1 + (size_t)r * DD + base + 4);
  float sa = u0.x * wa0.x + u0.y * wa0.y + u0.z * wa0.z + u0.w * wa0.w +
             u1.x * wa1.x + u1.y * wa1.y + u1.z * wa1.z + u1.w * wa1.w;
  float sb = u0.x * wb0.x + u0.y * wb0.y + u0.z * wb0.z + u0.w * wb0.w +
             u1.x * wb1.x + u1.y * wb1.y + u1.z * wb1.z + u1.w * wb1.w;
#pragma unroll
  for (int off = 32; off > 0; off >>= 1) {
    sa += __shfl_xor(sa, off);
    sb += __shfl_xor(sb, off);
  }
  if (lane == 0) { p.a1[r] = sa; p.b1[r] = sb; }
  wa0 = *(const float4*)(p.w11 + base);
  wa1 = *(const float4*)(p.w11 + base + 4);
  wb0 = *(const float4*)(p.w21 + base);
  wb1 = *(const float4*)(p.w21 + base + 4);
  u0 = *(const float4*)(p.U2 + (size_t)r * DD + base);
  u1 = *(const float4*)(p.U2 + (size_t)r * DD + base + 4);
  sa = u0.x * wa0.x + u0.y * wa0.y + u0.z * wa0.z + u0.w * wa0.w +
       u1.x * wa1.x + u1.y * wa1.y + u1.z * wa1.z + u1.w * wa1.w;
  sb = u0.x * wb0.x + u0.y * wb0.y + u0.z * wb0.z + u0.w * wb0.w +
       u1.x * wb1.x + u1.y * wb1.y + u1.z * wb1.z + u1.w * wb1.w;
#pragma unroll
  for (int off = 32; off > 0; off >>= 1) {
    sa += __shfl_xor(sa, off);
    sb += __shfl_xor(sb, off);
  }
  if (lane == 0) { p.a2[r] = sa; p.b2[r] = sb; }
}

// ---- SDDMM + softmax + dense scatter for ONE layer (lfix) -------------------
struct ScP {
  const int *cols, *cnts;
  const float *V, *U, *al, *be;
  const float* gam;
  const int* degA;
  float *av, *dense;   // dense != nullptr only for layer 1
  int lfix;
};

__global__ __launch_bounds__(256) void k_score(ScP p) {
  const int* cols = p.cols;
  const int* cnts = p.cnts;
  const float* V = p.V;
  const float* U = p.U;
  float* dense = p.dense;
  const int r = blockIdx.x;
  const int t = threadIdx.x;
  const int lane = t & 63, wv = t >> 6;
  const int cnt = cnts[r];
  __shared__ int scol[ELL];
  __shared__ float ssc[ELL];
  if (t < ELL) scol[t] = (t < cnt) ? cols[(size_t)r * ELL + t] : 0;
  if (dense) {
    float4 z = {0.f, 0.f, 0.f, 0.f};
    float4* drow = (float4*)(dense + (size_t)r * NN);
#pragma unroll
    for (int q = 0; q < 4; q++) drow[t + 256 * q] = z;
  }
  __syncthreads();
  const float g = p.gam[p.lfix];
  const float dr = (float)p.degA[r];
  const float ar = p.al[r];
  const float* Vr = V + (size_t)r * DD + lane * 8;
  float4 q0 = *(const float4*)Vr;
  float4 q1 = *(const float4*)(Vr + 4);
  for (int k = wv; k < cnt; k += 4) {
    const int c = scol[k];
    const float* Uc = U + (size_t)c * DD + lane * 8;
    float4 k0 = *(const float4*)Uc;
    float4 k1 = *(const float4*)(Uc + 4);
    float s = q0.x * k0.x + q0.y * k0.y + q0.z * k0.z + q0.w * k0.w +
              q1.x * k1.x + q1.y * k1.y + q1.z * k1.z + q1.w * k1.w;
#pragma unroll
    for (int off = 32; off > 0; off >>= 1) s += __shfl_xor(s, off);
    if (lane == 0) {
      const float dc = (float)p.degA[c];
      ssc[k] = s + dc * ar + dr * p.be[c] + dr * dc * g;
    }
  }
  __syncthreads();
  if (wv == 0) {
    float v0 = (lane < cnt) ? ssc[lane] : -INFINITY;
    float v1 = (lane + 64 < cnt) ? ssc[lane + 64] : -INFINITY;
    float mx = fmaxf(v0, v1);
#pragma unroll
    for (int off = 32; off > 0; off >>= 1) mx = fmaxf(mx, __shfl_xor(mx, off));
    float e0 = (lane < cnt) ? expf(v0 - mx) : 0.f;
    float e1 = (lane + 64 < cnt) ? expf(v1 - mx) : 0.f;
    float sm = e0 + e1;
#pragma unroll
    for (int off = 32; off > 0; off >>= 1) sm += __shfl_xor(sm, off);
    float inv = 1.f / sm;
    if (lane < cnt) ssc[lane] = e0 * inv;
    if (lane + 64 < cnt) ssc[lane + 64] = e1 * inv;
  }
  __syncthreads();
  if (t < cnt) {
    const float v = ssc[t];
    p.av[(size_t)r * ELL + t] = v;
    if (dense) dense[(size_t)r * NN + scol[t]] = v;
  }
}

// ---- panel PV: out[r, pan] = sum_k att_k * Tb[c_k, pan] (bf16, 1MB panels) --
struct PvP {
  const int *cols0, *cnts0, *cols1, *cnts1;
  const float *av0, *av1;
  const unsigned short *T0, *T1;
  float *out0, *out1;
};

__global__ __launch_bounds__(256) void k_pv_pan(PvP p) {
  const int bid = blockIdx.x;
  const int rgrp = bid & (NN / 4 - 1);
  const int g = bid / (NN / 4);
  const int pan = g & 3, l = g >> 2;
  const int* cols = l ? p.cols1 : p.cols0;
  const int* cnts = l ? p.cnts1 : p.cnts0;
  const float* av = l ? p.av1 : p.av0;
  const unsigned short* Tb = l ? p.T1 : p.T0;
  float* out = l ? p.out1 : p.out0;
  const int wv = threadIdx.x >> 6, lane = threadIdx.x & 63;
  const int row = rgrp * 4 + wv;
  __shared__ int scol[4][ELL];
  __shared__ float sval[4][ELL];
  const int cnt = cnts[row];
  for (int i = lane; i < ELL; i += 64) {
    scol[wv][i] = (i < cnt) ? cols[(size_t)row * ELL + i] : 0;
    sval[wv][i] = (i < cnt) ? av[(size_t)row * ELL + i] : 0.f;
  }
  const int cb = pan * 128 + lane * 2;
  float a0 = 0.f, a1 = 0.f;
#pragma unroll 4
  for (int k = 0; k < cnt; k++) {
    const float v = sval[wv][k];
    const unsigned u = *(const unsigned*)(Tb + (size_t)scol[wv][k] * DD + cb);
    a0 = fmaf(v, __uint_as_float(u << 16), a0);
    a1 = fmaf(v, __uint_as_float(u & 0xffff0000u), a1);
  }
  float2 o = {a0, a1};
  *(float2*)(out + (size_t)row * DD + cb) = o;
}

// ---- panel structural SpMM: C[r, pan] = sum_c B[c, pan] ---------------------
struct SpF {
  const int *colsA, *cntsA, *colsB, *cntsB;
  const float *BA, *BB;
  float *CA, *CB;
};

__global__ __launch_bounds__(256) void k_spmm_pan(SpF p) {
  const int bid = blockIdx.x;
  const int rgrp = bid & (NN / 4 - 1);
  const int g = bid / (NN / 4);
  const int pan = g & 3, mat = g >> 2;
  const int* cols = mat ? p.colsB : p.colsA;
  const int* cnts = mat ? p.cntsB : p.cntsA;
  const float* B = mat ? p.BB : p.BA;
  float* C = mat ? p.CB : p.CA;
  const int wv = threadIdx.x >> 6, lane = threadIdx.x & 63;
  const int row = rgrp * 4 + wv;
  __shared__ int scol[4][ELL];
  const int cnt = cnts[row];
  for (int i = lane; i < ELL; i += 64)
    scol[wv][i] = (i < cnt) ? cols[(size_t)row * ELL + i] : 0;
  const int cb = pan * 128 + lane * 2;
  float2 acc = {0.f, 0.f};
#pragma unroll 4
  for (int k = 0; k < cnt; k++) {
    const float2 b = *(const float2*)(B + (size_t)scol[wv][k] * DD + cb);
    acc.x += b.x;
    acc.y += b.y;
  }
  *(float2*)(C + (size_t)row * DD + cb) = acc;
}

// -------- fused: row-normalize 3 segments + mask + relu + classifier + lsm ---
__global__ __launch_bounds__(256) void k_norm_cls(const float* __restrict__ T0,
                                                  const float* __restrict__ T1,
                                                  const float* __restrict__ T2,
                                                  const float* __restrict__ hop,
                                                  const float* __restrict__ Wc,
                                                  const float* __restrict__ bc,
                                                  float* __restrict__ out) {
  const int r = blockIdx.x;
  const int t = threadIdx.x;
  const int lane = t & 63, wv = t >> 6;
  __shared__ __align__(16) float srow[1536];
  __shared__ float red[4];
  __shared__ float pr[6][40];
  float h0 = hop[0], h1 = hop[1], h2 = hop[2];
  float hm = fmaxf(h0, fmaxf(h1, h2));
  float e0 = expf(h0 - hm), e1 = expf(h1 - hm), e2 = expf(h2 - hm);
  float minv = 1.f / (e0 + e1 + e2);
  float mask[3] = {e0 * minv, e1 * minv, e2 * minv};
  const float* Ts[3] = {T0, T1, T2};
#pragma unroll
  for (int s = 0; s < 3; s++) {
    float x0 = Ts[s][(size_t)r * DD + t];
    float x1 = Ts[s][(size_t)r * DD + t + 256];
    float ss = x0 * x0 + x1 * x1;
#pragma unroll
    for (int off = 32; off > 0; off >>= 1) ss += __shfl_xor(ss, off);
    if (lane == 0) red[wv] = ss;
    __syncthreads();
    float tot = red[0] + red[1] + red[2] + red[3];
    float nrm = fmaxf(sqrtf(tot), 1e-12f);
    float sc = mask[s] / nrm;
    srow[s * DD + t] = fmaxf(x0 * sc, 0.f);
    srow[s * DD + t + 256] = fmaxf(x1 * sc, 0.f);
    __syncthreads();
  }
  float part = 0.f;
  const int col = t % 40, seg = t / 40;
  if (seg < 6) {
    const float* w = Wc + col;
#pragma unroll 4
    for (int k = seg * 256; k < seg * 256 + 256; k++)
      part = fmaf(srow[k], w[(size_t)k * 40], part);
    pr[seg][col] = part;
  }
  __syncthreads();
  if (t < 64) {
    float lg = -INFINITY;
    if (t < 40) {
      lg = bc[t];
#pragma unroll
      for (int s6 = 0; s6 < 6; s6++) lg += pr[s6][t];
    }
    float mx = lg;
#pragma unroll
    for (int off = 32; off > 0; off >>= 1) mx = fmaxf(mx, __shfl_xor(mx, off));
    float ex = (t < 40) ? expf(lg - mx) : 0.f;
    float sm = ex;
#pragma unroll
    for (int off = 32; off > 0; off >>= 1) sm += __shfl_xor(sm, off);
    float ls = logf(sm);
    if (t < 40) out[(size_t)r * 40 + t] = lg - mx - ls;
  }
}

extern "C" void kernel_launch(void* const* d_in, const int* in_sizes, int n_in,
                              void* d_out, int out_size, void* d_ws, size_t ws_size,
                              hipStream_t stream) {
  (void)in_sizes; (void)n_in; (void)out_size; (void)ws_size;
  const float* x    = (const float*)d_in[0];
  const float* adjA = (const float*)d_in[1];
  const float* adj1 = (const float*)d_in[2];
  const float* adj2 = (const float*)d_in[3];
  const float* hop  = (const float*)d_in[4];
  const float* Wfc0 = (const float*)d_in[5];  const float* bfc0 = (const float*)d_in[6];
  const float* Wfc1 = (const float*)d_in[7];  const float* bfc1 = (const float*)d_in[8];
  const float* Wfc2 = (const float*)d_in[9];  const float* bfc2 = (const float*)d_in[10];
  const float* Wq0  = (const float*)d_in[11]; const float* bq0  = (const float*)d_in[12];
  const float* Wk0  = (const float*)d_in[13]; const float* bk0  = (const float*)d_in[14];
  const float* Wq1  = (const float*)d_in[15]; const float* bq1  = (const float*)d_in[16];
  const float* Wk1  = (const float*)d_in[17]; const float* bk1  = (const float*)d_in[18];
  const float* Wc   = (const float*)d_in[19]; const float* bc   = (const float*)d_in[20];

  float* ws = (float*)d_ws;
  const size_t MD = (size_t)NN * DD;
  const size_t WD = (size_t)DD * DD;
  float* TMP0 = ws + 0 * MD;
  float* TMP1 = ws + 1 * MD;   // f32 tmp1; dead after spmm s1 -> reused as ATTV1
  float* TMP2 = ws + 2 * MD;   // f32 tmp2; dead after spmm s1 -> reused as ATTV2
  float* S3   = ws + 3 * MD;   // t_att1 -> V1 -> out1
  float* S4   = ws + 4 * MD;   // t_att2 -> V2 -> out2
  float* U1   = ws + 5 * MD;
  float* U2   = ws + 6 * MD;
  float* M1   = ws + 7 * MD;
  float* M2   = M1 + WD;
  float* w10 = M2 + WD;
  float* w20 = w10 + DD;
  float* w11 = w20 + DD;
  float* w21 = w11 + DD;
  float* gam = w21 + DD;
  float* AL1 = gam + 4;
  float* BE1 = AL1 + NN;
  float* AL2 = BE1 + NN;
  float* BE2 = AL2 + NN;
  int* ELLA = (int*)(BE2 + NN);
  int* ELL1 = ELLA + (size_t)NN * ELL;
  int* ELL2 = ELL1 + (size_t)NN * ELL;
  int* CNTA = ELL2 + (size_t)NN * ELL;
  int* CNT1 = CNTA + NN;
  int* CNT2 = CNT1 + NN;
  unsigned short* Tb1 = (unsigned short*)(CNT2 + NN);  // bf16 TMP1 (4 MB)
  unsigned short* Tb2 = Tb1 + MD;                      // bf16 TMP2 (4 MB)
  float* ATTV1 = TMP1;   // reuse: TMP1 f32 dead after spmm s1
  float* ATTV2 = TMP2;

  float* outLog = (float*)d_out;
  float* outAtt = outLog + (size_t)NN * 40;
  unsigned short* xb   = (unsigned short*)outAtt;
  unsigned short* wfcb = xb + 3 * MD;
  unsigned short* Ub1  = wfcb + 9 * WD;
  unsigned short* Ub2  = Ub1 + 3 * MD;
  unsigned short* Mb1  = Ub2 + 3 * MD;
  unsigned short* Mb2  = Mb1 + 3 * WD;

  Build3 pb{adjA, adj1, adj2, ELLA, ELL1, ELL2, CNTA, CNT1, CNT2};
  k_build3<<<dim3(NN, 3), 256, 0, stream>>>(pb);

  W12P pw{Wq0, bk0, Wk0, bq0, Wq1, bk1, Wk1, bq1, w10, w20, w11, w21, gam};
  k_w12<<<dim3(DD / 4, 2), 256, 0, stream>>>(pw);

  Split4 sp1{{{x, xb, NN, 0},
              {Wfc0, wfcb + 0 * 3 * WD, DD, 1},
              {Wfc1, wfcb + 1 * 3 * WD, DD, 1},
              {Wfc2, wfcb + 2 * 3 * WD, DD, 1}}};
  k_split<<<dim3(1024, 4), 256, 0, stream>>>(sp1);

  GmP pf{xb, xb, xb,
         wfcb + 0 * 3 * WD, wfcb + 1 * 3 * WD, wfcb + 2 * 3 * WD,
         bfc0, bfc1, bfc2, TMP0, TMP1, TMP2, MD, WD};
  k_gemm_mfma<<<dim3(32, 12), 256, 0, stream>>>(pf);

  GemmNT pm{Wq0, Wk0, Wq1, Wk1, M1, M2};
  k_gemm_nt<<<dim3(8, 16), 256, 0, stream>>>(pm);

  // bf16 copies of tmp1/tmp2 for the PV gather
  ToBf tb{TMP1, TMP2, Tb1, Tb2};
  k_tobf16<<<dim3(1024, 2), 256, 0, stream>>>(tb);

  // t_att_l = adjA @ tmp_l ; U_l = adjA @ t_att_l  (panel-temporal ordering)
  SpF s1{ELLA, CNTA, ELLA, CNTA, TMP1, TMP2, S3, S4};
  k_spmm_pan<<<8 * (NN / 4), 256, 0, stream>>>(s1);
  SpF s2{ELLA, CNTA, ELLA, CNTA, S3, S4, U1, U2};
  k_spmm_pan<<<8 * (NN / 4), 256, 0, stream>>>(s2);

  Split4 sp2{{{U1, Ub1, NN, 0},
              {U2, Ub2, NN, 0},
              {M1, Mb1, DD, 1},
              {M2, Mb2, DD, 1}}};
  k_split<<<dim3(1024, 4), 256, 0, stream>>>(sp2);

  GmP pv{Ub1, Ub2, nullptr, Mb1, Mb2, nullptr,
         nullptr, nullptr, nullptr, S3, S4, nullptr, MD, WD};
  k_gemm_mfma<<<dim3(32, 8), 256, 0, stream>>>(pv);

  AbP pab{U1, U2, w10, w20, w11, w21, AL1, BE1, AL2, BE2};
  k_ab<<<NN / 4, 256, 0, stream>>>(pab);

  // phase 1: per-layer score dispatches (halved concurrent gather working set)
  ScP sc0{ELL1, CNT1, S3, U1, AL1, BE1, gam, CNTA, ATTV1, nullptr, 0};
  k_score<<<NN, 256, 0, stream>>>(sc0);
  ScP sc1{ELL2, CNT2, S4, U2, AL2, BE2, gam, CNTA, ATTV2, outAtt, 1};
  k_score<<<NN, 256, 0, stream>>>(sc1);

  // phase 2: panel PV gather over bf16 tmp (1 MB concurrent working set)
  PvP pp{ELL1, CNT1, ELL2, CNT2, ATTV1, ATTV2, Tb1, Tb2, S3, S4};
  k_pv_pan<<<8 * (NN / 4), 256, 0, stream>>>(pp);

  k_norm_cls<<<NN, 256, 0, stream>>>(TMP0, S3, S4, hop, Wc, bc, outLog);
}